// Round 2
// baseline (2494.998 us; speedup 1.0000x reference)
//
#include <hip/hip_runtime.h>
#include <cstdint>
#include <cstddef>

// ViT block (SAM-style windowed attention, 14x14 windows, decomposed rel-pos).
// I/O fp32 (per reference); internal GEMM/attention compute in bf16 MFMA, fp32 acc.
// R2: GEMM rewritten to the 256x256 8-phase template (T2 swizzle + T3/T4 counted
//     vmcnt + T5 setprio + T1 XCD swizzle). 512 thr / 8 waves (2Mx4N), BK=64,
//     128 KiB LDS double-buffer, burst-staged global_load_lds with vmcnt(8).

typedef unsigned short u16;
typedef __attribute__((ext_vector_type(8))) short bf16x8;   // 8 bf16 = 4 VGPRs
typedef __attribute__((ext_vector_type(4))) short bf16x4;   // 8B
typedef __attribute__((ext_vector_type(4))) float f32x4;

#define MFMA16(a,b,c) __builtin_amdgcn_mfma_f32_16x16x32_bf16(a,b,c,0,0,0)

__device__ __forceinline__ float bf2f(u16 u){
  union { unsigned int i; float f; } v; v.i = ((unsigned int)u) << 16; return v.f;
}
__device__ __forceinline__ u16 f2bf(float f){
  union { float f; unsigned int i; } v; v.f = f;
  unsigned int r = v.i + 0x7FFFu + ((v.i >> 16) & 1u);   // RNE
  return (u16)(r >> 16);
}
__device__ __forceinline__ f32x4 f4zero(){ f32x4 z; z[0]=z[1]=z[2]=z[3]=0.f; return z; }
__device__ __forceinline__ bf16x8 ld8(const u16* p){ return *reinterpret_cast<const bf16x8*>(p); }

// async global->LDS, 16B per lane. LDS dest = wave-uniform base + lane*16.
__device__ __forceinline__ void gld_lds16(const u16* g, u16* l){
  __builtin_amdgcn_global_load_lds(
      (const __attribute__((address_space(1))) unsigned int*)(g),
      (__attribute__((address_space(3))) unsigned int*)(l), 16, 0, 0);
}

#define BAR   __builtin_amdgcn_s_barrier()
#define SB0   __builtin_amdgcn_sched_barrier(0)
#define PRIO1 __builtin_amdgcn_s_setprio(1)
#define PRIO0 __builtin_amdgcn_s_setprio(0)
#define VM8   asm volatile("s_waitcnt vmcnt(8)" ::: "memory")
#define VM0   asm volatile("s_waitcnt vmcnt(0)" ::: "memory")
#define LGKM0 asm volatile("s_waitcnt lgkmcnt(0)" ::: "memory")

// ------------------------------------------------ weight convert+transpose (fp32 -> bf16^T)
__global__ __launch_bounds__(256)
void conv_transpose(const float* __restrict__ in, u16* __restrict__ out, int R, int C)
{
  __shared__ float tile[32][33];
  int cb = C >> 5;
  int bx = blockIdx.x % cb, by = blockIdx.x / cb;
  int c0 = bx << 5, r0 = by << 5;
  int tx = threadIdx.x & 31, ty = threadIdx.x >> 5;   // ty 0..7
  #pragma unroll
  for (int k = 0; k < 4; k++)
    tile[ty + 8*k][tx] = in[(size_t)(r0 + ty + 8*k) * C + c0 + tx];
  __syncthreads();
  #pragma unroll
  for (int k = 0; k < 4; k++)
    out[(size_t)(c0 + ty + 8*k) * R + r0 + tx] = f2bf(tile[tx][ty + 8*k]);
}

// ------------------------------------------------ rel-pos table convert (fp32 -> bf16)
__global__ __launch_bounds__(256)
void conv_bf16(const float* __restrict__ a, const float* __restrict__ b,
               u16* __restrict__ oa, u16* __restrict__ ob, int n)
{
  int i = blockIdx.x * 256 + threadIdx.x;
  if (i < n){ oa[i] = f2bf(a[i]); ob[i] = f2bf(b[i]); }
}

// ------------------------------------------------ layernorm (fp32 in -> bf16 out)
__global__ __launch_bounds__(256)
void ln_kernel(const float* __restrict__ in, const float* __restrict__ g,
               const float* __restrict__ b, u16* __restrict__ out, int window_map)
{
  const int wv = threadIdx.x >> 6, lane = threadIdx.x & 63;
  const int token = blockIdx.x * 4 + wv;
  const float* row = in + (size_t)token * 768;
  float vals[12];
  float s = 0.f, s2 = 0.f;
  #pragma unroll
  for (int j = 0; j < 3; j++){
    float4 u = *reinterpret_cast<const float4*>(row + j*256 + lane*4);
    float t[4] = {u.x, u.y, u.z, u.w};
    #pragma unroll
    for (int e = 0; e < 4; e++){ vals[j*4+e] = t[e]; s += t[e]; s2 += t[e]*t[e]; }
  }
  #pragma unroll
  for (int m = 1; m < 64; m <<= 1){ s += __shfl_xor(s, m, 64); s2 += __shfl_xor(s2, m, 64); }
  float mu  = s  * (1.f/768.f);
  float var = s2 * (1.f/768.f) - mu*mu;
  float rs  = rsqrtf(var + 1e-5f);
  size_t orow = (size_t)token;
  if (window_map){
    int b_ = token / 3136, rem = token % 3136;
    int hh = rem / 56, ww = rem % 56;
    int win = ((b_ << 2) + hh/14)*4 + ww/14;
    orow = (size_t)win * 196 + (hh%14)*14 + (ww%14);
  }
  u16* op = out + orow * 768;
  #pragma unroll
  for (int j = 0; j < 3; j++){
    int cb = j*256 + lane*4;
    float4 gg = *reinterpret_cast<const float4*>(g + cb);
    float4 bb = *reinterpret_cast<const float4*>(b + cb);
    float gt[4] = {gg.x, gg.y, gg.z, gg.w};
    float bt[4] = {bb.x, bb.y, bb.z, bb.w};
    bf16x4 o;
    #pragma unroll
    for (int e = 0; e < 4; e++)
      o[e] = (short)f2bf((vals[j*4+e] - mu) * rs * gt[e] + bt[e]);
    *reinterpret_cast<bf16x4*>(op + cb) = o;
  }
}

// ------------------------------------------------ GEMM: 256x256 tile, 8-phase
// C[M,N] = A[M,K] @ Bt[N,K]^T (+bias +epilogue). 512 thr = 8 waves (2M x 4N);
// wave owns 128x64 output. BK=64 (2 MFMA-k per frag pair). LDS: 2 buf x (A,B) x
// 256x64 bf16 = 128 KiB. LDS swizzle: byte ^= ((row&7)<<4) (8 bank-starts, 2-way
// free). Staging: 8 global_load_lds/wave/tile, pre-swizzled global src (involution),
// burst-issued at tile boundaries after the trailing barrier (write-after-read
// airtight), waited with vmcnt(8) one tile later (loads span 4 phases, never
// drained to 0 in steady state).
enum { EPI_QKV = 0, EPI_PROJ = 1, EPI_GELU = 2, EPI_MLP2 = 3 };

__global__ __launch_bounds__(512, 2)
void gemm256(const u16* __restrict__ A, const u16* __restrict__ Bt,
             const float* __restrict__ bias, const float* __restrict__ residf,
             void* __restrict__ outp, int M, int N, int K, int epi)
{
  __shared__ u16 lds[2][2][16384];   // [buf][A=0/B=1][256 rows x 64 cols], 128 KiB
  const int nbn = N >> 8;
  // T1: bijective XCD swizzle (m204)
  const int nwg = gridDim.x;
  const int orig = blockIdx.x;
  const int qq = nwg >> 3, rr = nwg & 7;
  const int xcd = orig & 7, idx = orig >> 3;
  const int wg = (xcd < rr ? xcd*(qq+1) : rr*(qq+1) + (xcd-rr)*qq) + idx;
  const int bm = wg / nbn, bn = wg % nbn;
  const int m0 = bm << 8, n0 = bn << 8;
  const int tid = threadIdx.x;
  const int wv = tid >> 6, lane = tid & 63;
  const int q = lane >> 4, c = lane & 15;
  const int wmI = wv >> 2, wnI = wv & 3;      // 2 x 4 wave grid

  f32x4 acc[8][4];
  #pragma unroll
  for (int i = 0; i < 8; i++)
    #pragma unroll
    for (int j = 0; j < 4; j++) acc[i][j] = f4zero();

  // staging per-lane geometry: instr j covers physical 1KB (w*2+j) of a 16KB half.
  // physical p -> logical b via involution b = p ^ (((p>>7)&7)<<4).
  int offA[2][2], offB[2][2];   // element offsets (fit in int32 for all our sizes)
  #pragma unroll
  for (int j = 0; j < 2; j++){
    int p = ((wv*2 + j) << 10) + lane*16;
    int b = p ^ (((p >> 7) & 7) << 4);
    int brow = b >> 7;            // 0..127 within half
    int bcol = (b & 127) >> 1;    // element col 0..63
    #pragma unroll
    for (int h = 0; h < 2; h++){
      offA[j][h] = (m0 + h*128 + brow) * K + bcol;
      offB[j][h] = (n0 + h*128 + brow) * K + bcol;
    }
  }

  #define STAGE(BB, T) do {                                              \
    int ko_ = (T) << 6;                                                  \
    _Pragma("unroll") for (int j_ = 0; j_ < 2; j_++)                     \
    _Pragma("unroll") for (int h_ = 0; h_ < 2; h_++){                    \
      gld_lds16(A  + offA[j_][h_] + ko_,                                 \
                &lds[BB][0][h_*8192 + (wv*2 + j_)*512]);                 \
      gld_lds16(Bt + offB[j_][h_] + ko_,                                 \
                &lds[BB][1][h_*8192 + (wv*2 + j_)*512]);                 \
    }                                                                    \
  } while(0)

  // fragment read addressing (swizzled): row&7 == c&7 for both A and B bases.
  const int rA0 = wmI*128 + c;
  const int rB0 = wnI*64 + c;
  const int xb[2] = { (q*16) ^ ((c & 7) << 4), (64 + q*16) ^ ((c & 7) << 4) };

  #define RD_A(BB, MH, I, KS)                                            \
    af[I][KS] = ld8((const u16*)((const char*)&lds[BB][0][0] +           \
                    (((rA0 + (MH)*64 + (I)*16) << 7) + xb[KS])))
  #define RD_B0(BB, NN, KS)                                              \
    bq0[NN][KS] = ld8((const u16*)((const char*)&lds[BB][1][0] +         \
                    (((rB0 + (NN)*16) << 7) + xb[KS])))
  #define RD_B1(BB, NN, KS)                                              \
    bq1[NN][KS] = ld8((const u16*)((const char*)&lds[BB][1][0] +         \
                    (((rB0 + 32 + (NN)*16) << 7) + xb[KS])))

  #define MMQ(MH, NH, BQ)                                                \
    _Pragma("unroll") for (int i_ = 0; i_ < 4; i_++)                     \
    _Pragma("unroll") for (int n_ = 0; n_ < 2; n_++)                     \
    _Pragma("unroll") for (int k_ = 0; k_ < 2; k_++)                     \
      acc[(MH)*4+i_][(NH)*2+n_] =                                        \
        MFMA16(af[i_][k_], BQ[n_][k_], acc[(MH)*4+i_][(NH)*2+n_])

  bf16x8 af[4][2], bq0[2][2], bq1[2][2];

  // 4 phases per K-tile: Q0(12 reads), Q1(4), Q2(8), Q3(0)
  #define TILE4(BB) do {                                                 \
    _Pragma("unroll") for (int i_ = 0; i_ < 4; i_++){                    \
      RD_A(BB, 0, i_, 0); RD_A(BB, 0, i_, 1); }                          \
    _Pragma("unroll") for (int n_ = 0; n_ < 2; n_++){                    \
      RD_B0(BB, n_, 0); RD_B0(BB, n_, 1); }                              \
    BAR; LGKM0; SB0; PRIO1; MMQ(0,0,bq0); PRIO0; BAR; SB0;               \
    _Pragma("unroll") for (int n_ = 0; n_ < 2; n_++){                    \
      RD_B1(BB, n_, 0); RD_B1(BB, n_, 1); }                              \
    BAR; LGKM0; SB0; PRIO1; MMQ(0,1,bq1); PRIO0; BAR; SB0;               \
    _Pragma("unroll") for (int i_ = 0; i_ < 4; i_++){                    \
      RD_A(BB, 1, i_, 0); RD_A(BB, 1, i_, 1); }                          \
    BAR; LGKM0; SB0; PRIO1; MMQ(1,0,bq0); PRIO0; BAR; SB0;               \
    PRIO1; MMQ(1,1,bq1); PRIO0; BAR; SB0;                                \
  } while(0)

  const int nT = K >> 6;
  STAGE(0, 0); STAGE(1, 1);
  VM8; BAR; SB0;                       // tile0 landed; tile1 in flight
  for (int t = 0; t < nT; t += 2){
    TILE4(0);
    if (t + 2 < nT){ STAGE(0, t+2); VM8; } else { VM0; }
    BAR; SB0;
    TILE4(1);
    if (t + 3 < nT){ STAGE(1, t+3); VM8; BAR; SB0; }
  }

  // epilogue (D[row=q*4+reg][col=lane&15] per 16x16 fragment)
  const int mrow0 = m0 + wmI*128;
  const int ncol0 = n0 + wnI*64;
  #pragma unroll
  for (int mi = 0; mi < 8; mi++){
    #pragma unroll
    for (int r = 0; r < 4; r++){
      int grow = mrow0 + mi*16 + q*4 + r;
      size_t orow = (size_t)grow;
      if (epi == EPI_PROJ){   // window-order row -> standard (b,h,w) row
        int win = grow / 196, loc = grow % 196;
        int b_ = win >> 4, wr = win & 15;
        int hh = (wr >> 2) * 14 + loc / 14;
        int ww = (wr & 3)  * 14 + loc % 14;
        orow = (size_t)((b_ * 56 + hh) * 56 + ww);
      }
      #pragma unroll
      for (int ni = 0; ni < 4; ni++){
        int col = ncol0 + ni*16 + c;
        float v = acc[mi][ni][r] + bias[col];
        if (epi == EPI_PROJ){           // + x (shortcut), fp32 out
          v += residf[orow * 768 + col];
          ((float*)outp)[orow * (size_t)N + col] = v;
        } else if (epi == EPI_MLP2){    // + hidden, fp32 out (in-place safe)
          v += residf[(size_t)grow * 768 + col];
          ((float*)outp)[orow * (size_t)N + col] = v;
        } else {
          if (epi == EPI_GELU) v = 0.5f * v * (1.f + erff(v * 0.70710678f));
          ((u16*)outp)[orow * (size_t)N + col] = f2bf(v);
        }
      }
    }
  }
  #undef STAGE
  #undef RD_A
  #undef RD_B0
  #undef RD_B1
  #undef MMQ
  #undef TILE4
}

// ------------------------------------------------ attention (unchanged this round)
__global__ __launch_bounds__(256)
void attn_kernel(const u16* __restrict__ qkv, const u16* __restrict__ relh,
                 const u16* __restrict__ relw, u16* __restrict__ aout)
{
  __shared__ u16 Vt[64][232];          // [hd][token 0..223 +pad]; cols >=196 zeroed
  __shared__ u16 P[4][16*216 + 16];    // per-wave P tile, rows stride 216, 16-elem tail
  __shared__ u16 RB[4][16][56];        // per-wave bias: [row][dh 0..26 | 28+dw 0..26]
  const int blk = blockIdx.x;
  const int win = blk / 12, head = blk % 12;
  const int tid = threadIdx.x;
  const int wv = tid >> 6, lane = tid & 63;
  const int q = lane >> 4, c = lane & 15;
  const u16* base = qkv + (size_t)win * 196 * 2304 + head * 64;

  for (int i = tid; i < 64*36; i += 256) Vt[i / 36][196 + i % 36] = 0;
  for (int i = tid; i < 4*144; i += 256){
    int w = i / 144, r = i % 144;
    int off = (r < 128) ? ((r >> 3) * 216 + 208 + (r & 7)) : (16*216 + (r - 128));
    P[w][off] = 0;
  }
  for (int i = tid; i < 196*8; i += 256){
    int t = i >> 3, h8 = (i & 7) << 3;
    bf16x8 v = ld8(base + (size_t)t * 2304 + 1536 + h8);
    #pragma unroll
    for (int j = 0; j < 8; j++) Vt[h8 + j][t] = (u16)v[j];
  }
  __syncthreads();

  const float scale = 0.125f;   // 64^-0.5
  for (int mt = wv; mt < 13; mt += 4){
    const int m0 = mt * 16;
    int qr = m0 + c; if (qr > 195) qr = 195;
    const u16* qrow = base + (size_t)qr * 2304;
    bf16x8 aq0 = ld8(qrow + q*8);
    bf16x8 aq1 = ld8(qrow + 32 + q*8);

    f32x4 accs[13];
    #pragma unroll
    for (int nt = 0; nt < 13; nt++) accs[nt] = f4zero();
    #pragma unroll
    for (int nt = 0; nt < 13; nt++){
      int kt = nt*16 + c; if (kt > 195) kt = 195;
      const u16* krow = base + (size_t)kt * 2304 + 768;
      accs[nt] = MFMA16(aq0, ld8(krow + q*8), accs[nt]);
      accs[nt] = MFMA16(aq1, ld8(krow + 32 + q*8), accs[nt]);
    }

    f32x4 rha[2], rwa[2];
    #pragma unroll
    for (int ntt = 0; ntt < 2; ntt++){
      int dh = ntt*16 + c; if (dh > 26) dh = 26;
      const u16* ph = relh + dh*64;
      const u16* pw = relw + dh*64;
      rha[ntt] = MFMA16(aq0, ld8(ph + q*8), f4zero());
      rha[ntt] = MFMA16(aq1, ld8(ph + 32 + q*8), rha[ntt]);
      rwa[ntt] = MFMA16(aq0, ld8(pw + q*8), f4zero());
      rwa[ntt] = MFMA16(aq1, ld8(pw + 32 + q*8), rwa[ntt]);
    }
    #pragma unroll
    for (int ntt = 0; ntt < 2; ntt++)
      #pragma unroll
      for (int r = 0; r < 4; r++){
        int col = ntt*16 + c;
        if (col < 27){
          RB[wv][q*4+r][col]      = f2bf(rha[ntt][r]);
          RB[wv][q*4+r][28 + col] = f2bf(rwa[ntt][r]);
        }
      }

    #pragma unroll
    for (int r = 0; r < 4; r++){
      int it = m0 + q*4 + r; if (it > 195) it = 195;
      int hq = it / 14, wq = it % 14;
      float sv[13];
      float mx = -3e38f;
      #pragma unroll
      for (int nt = 0; nt < 13; nt++){
        int j = nt*16 + c;
        float x;
        if (j < 196){
          int hk = j / 14, wk = j % 14;
          x = accs[nt][r] * scale + bf2f(RB[wv][q*4+r][hq - hk + 13])
                                  + bf2f(RB[wv][q*4+r][28 + wq - wk + 13]);
        } else x = -3e38f;
        sv[nt] = x; mx = fmaxf(mx, x);
      }
      mx = fmaxf(mx, __shfl_xor(mx, 1, 64));
      mx = fmaxf(mx, __shfl_xor(mx, 2, 64));
      mx = fmaxf(mx, __shfl_xor(mx, 4, 64));
      mx = fmaxf(mx, __shfl_xor(mx, 8, 64));
      float sum = 0.f;
      #pragma unroll
      for (int nt = 0; nt < 13; nt++){ float p = __expf(sv[nt] - mx); sv[nt] = p; sum += p; }
      sum += __shfl_xor(sum, 1, 64); sum += __shfl_xor(sum, 2, 64);
      sum += __shfl_xor(sum, 4, 64); sum += __shfl_xor(sum, 8, 64);
      float is = 1.f / sum;
      #pragma unroll
      for (int nt = 0; nt < 13; nt++)
        P[wv][(q*4+r)*216 + nt*16 + c] = f2bf(sv[nt] * is);
    }

    f32x4 acco[4];
    #pragma unroll
    for (int nv = 0; nv < 4; nv++) acco[nv] = f4zero();
    #pragma unroll
    for (int ks = 0; ks < 7; ks++){
      bf16x8 ap = ld8(&P[wv][c*216 + ks*32 + q*8]);
      #pragma unroll
      for (int nv = 0; nv < 4; nv++){
        bf16x8 bv = ld8(&Vt[nv*16 + c][ks*32 + q*8]);
        acco[nv] = MFMA16(ap, bv, acco[nv]);
      }
    }
    #pragma unroll
    for (int nv = 0; nv < 4; nv++)
      #pragma unroll
      for (int r = 0; r < 4; r++){
        int it = m0 + q*4 + r;
        if (it < 196)
          aout[(size_t)(win*196 + it)*768 + head*64 + nv*16 + c] = f2bf(acco[nv][r]);
      }
  }
}

// ------------------------------------------------ launch
extern "C" void kernel_launch(void* const* d_in, const int* in_sizes, int n_in,
                              void* d_out, int out_size, void* d_ws, size_t ws_size,
                              hipStream_t stream)
{
  (void)in_sizes; (void)n_in; (void)out_size; (void)ws_size;
  const float* x      = (const float*)d_in[0];
  const float* n1g    = (const float*)d_in[1];
  const float* n1b    = (const float*)d_in[2];
  const float* qkv_w  = (const float*)d_in[3];
  const float* qkv_b  = (const float*)d_in[4];
  const float* proj_w = (const float*)d_in[5];
  const float* proj_b = (const float*)d_in[6];
  const float* relh   = (const float*)d_in[7];
  const float* relw   = (const float*)d_in[8];
  const float* n2g    = (const float*)d_in[9];
  const float* n2b    = (const float*)d_in[10];
  const float* lin1_w = (const float*)d_in[11];
  const float* lin1_b = (const float*)d_in[12];
  const float* lin2_w = (const float*)d_in[13];
  const float* lin2_b = (const float*)d_in[14];
  float* out = (float*)d_out;   // also serves as fp32 'hidden' buffer

  char* ws = (char*)d_ws;
  u16* qkvwt  = (u16*)(ws);                        //  3,538,944 B
  u16* projwt = (u16*)(ws +  3538944);             //  1,179,648 B
  u16* lin1wt = (u16*)(ws +  4718592);             //  4,718,592 B
  u16* lin2wt = (u16*)(ws +  9437184);             //  4,718,592 B
  u16* relhb  = (u16*)(ws + 14155776);             //      3,456 B
  u16* relwb  = (u16*)(ws + 14159232);             //      3,456 B
  u16* bufA   = (u16*)(ws + 14162688);             // 77,070,336 B: ln1out -> attnout -> normed
  u16* bufQ   = (u16*)(ws + 14162688 + (size_t)77070336); // 231,211,008 B: qkv -> m1 chunks

  conv_transpose<<<(768/32)*(2304/32), 256, 0, stream>>>(qkv_w,  qkvwt, 768, 2304);
  conv_transpose<<<(768/32)*(768/32),  256, 0, stream>>>(proj_w, projwt, 768, 768);
  conv_transpose<<<(768/32)*(3072/32), 256, 0, stream>>>(lin1_w, lin1wt, 768, 3072);
  conv_transpose<<<(3072/32)*(768/32), 256, 0, stream>>>(lin2_w, lin2wt, 3072, 768);
  conv_bf16<<<(27*64 + 255)/256, 256, 0, stream>>>(relh, relw, relhb, relwb, 27*64);

  // LN1 (window-ordered bf16) -> QKV GEMM -> attention
  ln_kernel<<<12544, 256, 0, stream>>>(x, n1g, n1b, bufA, 1);
  gemm256<<<196*9, 512, 0, stream>>>(bufA, qkvwt, qkv_b, nullptr, bufQ,
                                     50176, 2304, 768, EPI_QKV);
  attn_kernel<<<3072, 256, 0, stream>>>(bufQ, relhb, relwb, bufA);
  // proj + residual -> hidden (fp32, in d_out)
  gemm256<<<196*3, 512, 0, stream>>>(bufA, projwt, proj_b, x, out,
                                     50176, 768, 768, EPI_PROJ);
  // LN2 -> MLP (2 halves; m1 reuses bufQ)
  ln_kernel<<<12544, 256, 0, stream>>>(out, n2g, n2b, bufA, 0);
  for (int h = 0; h < 2; h++){
    const u16* nrm = bufA + (size_t)h * 25088 * 768;
    float* hid     = out  + (size_t)h * 25088 * 768;
    gemm256<<<98*12, 512, 0, stream>>>(nrm, lin1wt, lin1_b, nullptr, bufQ,
                                       25088, 3072, 768, EPI_GELU);
    gemm256<<<98*3, 512, 0, stream>>>(bufQ, lin2wt, lin2_b, hid, hid,
                                      25088, 768, 3072, EPI_MLP2);
  }
}

// Round 3
// 2353.951 us; speedup vs baseline: 1.0599x; 1.0599x over previous
//
#include <hip/hip_runtime.h>
#include <cstdint>
#include <cstddef>

// ViT block (SAM-style windowed attention, 14x14 windows, decomposed rel-pos).
// I/O fp32 (per reference); internal GEMM/attention compute in bf16 MFMA, fp32 acc.
// R3: gemm256 rescheduled to the faithful fine-interleave 8-phase template:
//     phases = block C-quadrants (128x128) so each phase reads exactly one A-half
//     and one B-half -> halves die incrementally -> race-free 1-half-per-phase
//     staging into dead regions, counted vmcnt(4) at phases 4/8 only (never 0 in
//     steady state). T2 swizzle + T5 setprio kept; T1 bijective XCD swizzle kept.

typedef unsigned short u16;
typedef __attribute__((ext_vector_type(8))) short bf16x8;   // 8 bf16 = 4 VGPRs
typedef __attribute__((ext_vector_type(4))) short bf16x4;   // 8B
typedef __attribute__((ext_vector_type(4))) float f32x4;

#define MFMA16(a,b,c) __builtin_amdgcn_mfma_f32_16x16x32_bf16(a,b,c,0,0,0)

__device__ __forceinline__ float bf2f(u16 u){
  union { unsigned int i; float f; } v; v.i = ((unsigned int)u) << 16; return v.f;
}
__device__ __forceinline__ u16 f2bf(float f){
  union { float f; unsigned int i; } v; v.f = f;
  unsigned int r = v.i + 0x7FFFu + ((v.i >> 16) & 1u);   // RNE
  return (u16)(r >> 16);
}
__device__ __forceinline__ f32x4 f4zero(){ f32x4 z; z[0]=z[1]=z[2]=z[3]=0.f; return z; }
__device__ __forceinline__ bf16x8 ld8(const u16* p){ return *reinterpret_cast<const bf16x8*>(p); }

// async global->LDS, 16B per lane. LDS dest = wave-uniform base + lane*16.
__device__ __forceinline__ void gld_lds16(const u16* g, u16* l){
  __builtin_amdgcn_global_load_lds(
      (const __attribute__((address_space(1))) unsigned int*)(g),
      (__attribute__((address_space(3))) unsigned int*)(l), 16, 0, 0);
}

#define BAR   __builtin_amdgcn_s_barrier()
#define SB0   __builtin_amdgcn_sched_barrier(0)
#define PRIO1 __builtin_amdgcn_s_setprio(1)
#define PRIO0 __builtin_amdgcn_s_setprio(0)
#define VM4   asm volatile("s_waitcnt vmcnt(4)" ::: "memory")
#define VM0   asm volatile("s_waitcnt vmcnt(0)" ::: "memory")
#define LGKM0 asm volatile("s_waitcnt lgkmcnt(0)" ::: "memory")

// ------------------------------------------------ weight convert+transpose (fp32 -> bf16^T)
__global__ __launch_bounds__(256)
void conv_transpose(const float* __restrict__ in, u16* __restrict__ out, int R, int C)
{
  __shared__ float tile[32][33];
  int cb = C >> 5;
  int bx = blockIdx.x % cb, by = blockIdx.x / cb;
  int c0 = bx << 5, r0 = by << 5;
  int tx = threadIdx.x & 31, ty = threadIdx.x >> 5;   // ty 0..7
  #pragma unroll
  for (int k = 0; k < 4; k++)
    tile[ty + 8*k][tx] = in[(size_t)(r0 + ty + 8*k) * C + c0 + tx];
  __syncthreads();
  #pragma unroll
  for (int k = 0; k < 4; k++)
    out[(size_t)(c0 + ty + 8*k) * R + r0 + tx] = f2bf(tile[tx][ty + 8*k]);
}

// ------------------------------------------------ rel-pos table convert (fp32 -> bf16)
__global__ __launch_bounds__(256)
void conv_bf16(const float* __restrict__ a, const float* __restrict__ b,
               u16* __restrict__ oa, u16* __restrict__ ob, int n)
{
  int i = blockIdx.x * 256 + threadIdx.x;
  if (i < n){ oa[i] = f2bf(a[i]); ob[i] = f2bf(b[i]); }
}

// ------------------------------------------------ layernorm (fp32 in -> bf16 out)
__global__ __launch_bounds__(256)
void ln_kernel(const float* __restrict__ in, const float* __restrict__ g,
               const float* __restrict__ b, u16* __restrict__ out, int window_map)
{
  const int wv = threadIdx.x >> 6, lane = threadIdx.x & 63;
  const int token = blockIdx.x * 4 + wv;
  const float* row = in + (size_t)token * 768;
  float vals[12];
  float s = 0.f, s2 = 0.f;
  #pragma unroll
  for (int j = 0; j < 3; j++){
    float4 u = *reinterpret_cast<const float4*>(row + j*256 + lane*4);
    float t[4] = {u.x, u.y, u.z, u.w};
    #pragma unroll
    for (int e = 0; e < 4; e++){ vals[j*4+e] = t[e]; s += t[e]; s2 += t[e]*t[e]; }
  }
  #pragma unroll
  for (int m = 1; m < 64; m <<= 1){ s += __shfl_xor(s, m, 64); s2 += __shfl_xor(s2, m, 64); }
  float mu  = s  * (1.f/768.f);
  float var = s2 * (1.f/768.f) - mu*mu;
  float rs  = rsqrtf(var + 1e-5f);
  size_t orow = (size_t)token;
  if (window_map){
    int b_ = token / 3136, rem = token % 3136;
    int hh = rem / 56, ww = rem % 56;
    int win = ((b_ << 2) + hh/14)*4 + ww/14;
    orow = (size_t)win * 196 + (hh%14)*14 + (ww%14);
  }
  u16* op = out + orow * 768;
  #pragma unroll
  for (int j = 0; j < 3; j++){
    int cb = j*256 + lane*4;
    float4 gg = *reinterpret_cast<const float4*>(g + cb);
    float4 bb = *reinterpret_cast<const float4*>(b + cb);
    float gt[4] = {gg.x, gg.y, gg.z, gg.w};
    float bt[4] = {bb.x, bb.y, bb.z, bb.w};
    bf16x4 o;
    #pragma unroll
    for (int e = 0; e < 4; e++)
      o[e] = (short)f2bf((vals[j*4+e] - mu) * rs * gt[e] + bt[e]);
    *reinterpret_cast<bf16x4*>(op + cb) = o;
  }
}

// ------------------------------------------------ GEMM: 256x256 tile, 8-phase fine interleave
// C[M,N] = A[M,K] @ Bt[N,K]^T (+bias +epilogue). 512 thr = 8 waves (2M x 4N).
// Phase = block C-quadrant (128x128) x K=64: reads ONE A-half + ONE B-half.
// Wave sub-tile per phase: 64x32 -> 16 MFMA; acc[qm][qn][4][2] f32x4 (128 VGPR).
// LDS: [2 buf][A,B][2 half][16KB] = 128 KiB; halves staged 1/phase into regions
// that died the previous phase (content 2 K-tiles ahead); vmcnt(4) at phases 4/8.
// LDS swizzle: byte ^= ((row&7)<<4); gld_lds sources pre-swizzled (involution).
enum { EPI_QKV = 0, EPI_PROJ = 1, EPI_GELU = 2, EPI_MLP2 = 3 };

__global__ __launch_bounds__(512, 2)
void gemm256(const u16* __restrict__ A, const u16* __restrict__ Bt,
             const float* __restrict__ bias, const float* __restrict__ residf,
             void* __restrict__ outp, int M, int N, int K, int epi)
{
  __shared__ u16 lds[2][2][2][8192];   // [buf][A=0/B=1][half][128 rows x 64 cols]
  const int nbn = N >> 8;
  // T1: bijective XCD swizzle (m204)
  const int nwg = gridDim.x;
  const int orig = blockIdx.x;
  const int qq = nwg >> 3, rr = nwg & 7;
  const int xcd = orig & 7, idx = orig >> 3;
  const int wg = (xcd < rr ? xcd*(qq+1) : rr*(qq+1) + (xcd-rr)*qq) + idx;
  const int bm = wg / nbn, bn = wg % nbn;
  const int m0 = bm << 8, n0 = bn << 8;
  const int tid = threadIdx.x;
  const int wv = tid >> 6, lane = tid & 63;
  const int q = lane >> 4, c = lane & 15;
  const int wmI = wv >> 2, wnI = wv & 3;      // 2 x 4 wave grid

  f32x4 acc[2][2][4][2];
  #pragma unroll
  for (int a_ = 0; a_ < 2; a_++)
    #pragma unroll
    for (int b_ = 0; b_ < 2; b_++)
      #pragma unroll
      for (int i_ = 0; i_ < 4; i_++)
        #pragma unroll
        for (int n_ = 0; n_ < 2; n_++) acc[a_][b_][i_][n_] = f4zero();

  // staging geometry (verified in R2): instr j covers physical 1KB chunk (wv*2+j)
  // of a 16KB half; logical = physical ^ (((p>>7)&7)<<4) involution.
  int offA[2][2], offB[2][2];   // [j][half] element offsets
  #pragma unroll
  for (int j = 0; j < 2; j++){
    int p = ((wv*2 + j) << 10) + lane*16;
    int b = p ^ (((p >> 7) & 7) << 4);
    int brow = b >> 7;            // 0..127 within half
    int bcol = (b & 127) >> 1;    // element col 0..63
    #pragma unroll
    for (int h = 0; h < 2; h++){
      offA[j][h] = (m0 + h*128 + brow) * K + bcol;
      offB[j][h] = (n0 + h*128 + brow) * K + bcol;
    }
  }

  // stage one half: (buf BB, operand OP, half HH) <- K-tile T
  #define STG(BB, OP, HH, T) do {                                        \
    _Pragma("unroll") for (int j_ = 0; j_ < 2; j_++)                     \
      gld_lds16(((OP) ? Bt : A) + ((OP) ? offB : offA)[j_][HH] + ((T) << 6), \
                &lds[BB][OP][HH][(wv*2 + j_)*512]);                      \
  } while(0)

  // fragment reads (swizzled). row-in-half bases:
  const int rA = wmI*64 + c;            // A: wave's 64-row slice within the half
  const int rB = wnI*32 + c;            // B: wave's 32-row slice within the half
  const int xb[2] = { (q*16) ^ ((c & 7) << 4), (64 + q*16) ^ ((c & 7) << 4) };

  bf16x8 af[4][2], bq0[2][2], bq1[2][2];

  #define RD_A(BB, QM) do {                                              \
    _Pragma("unroll") for (int i_ = 0; i_ < 4; i_++)                     \
    _Pragma("unroll") for (int k_ = 0; k_ < 2; k_++)                     \
      af[i_][k_] = ld8((const u16*)((const char*)&lds[BB][0][QM][0] +    \
                       ((rA << 7) + (i_ << 11) + xb[k_])));              \
  } while(0)
  #define RD_B(BB, QN, BQ) do {                                          \
    _Pragma("unroll") for (int n_ = 0; n_ < 2; n_++)                     \
    _Pragma("unroll") for (int k_ = 0; k_ < 2; k_++)                     \
      BQ[n_][k_] = ld8((const u16*)((const char*)&lds[BB][1][QN][0] +    \
                       ((rB << 7) + (n_ << 11) + xb[k_])));              \
  } while(0)
  #define MM(QM, QN, BQ) do {                                            \
    _Pragma("unroll") for (int i_ = 0; i_ < 4; i_++)                     \
    _Pragma("unroll") for (int n_ = 0; n_ < 2; n_++)                     \
    _Pragma("unroll") for (int k_ = 0; k_ < 2; k_++)                     \
      acc[QM][QN][i_][n_] = MFMA16(af[i_][k_], BQ[n_][k_],               \
                                   acc[QM][QN][i_][n_]);                 \
  } while(0)

  const int nT = K >> 6;   // 12 (K=768) or 48 (K=3072)

  // prologue: tile0 all 4 halves + tile1 h0 of A and B (6 halves, 12 loads)
  STG(0,0,0, 0); STG(0,1,0, 0); STG(0,0,1, 0); STG(0,1,1, 0);
  STG(1,0,0, 1); STG(1,1,0, 1);
  VM4; BAR; SB0;          // tile0 landed; tile1-h0 pair may be in flight

  for (int t = 0; t < nT; t += 2){
    const bool more = (t + 2 < nT);
    // P1: tile t quad(0,0); stage buf1.A.h1 <- t+1 (region died iter-prev P8)
    RD_A(0, 0); RD_B(0, 0, bq0);
    STG(1,0,1, t+1);
    BAR; LGKM0; SB0; PRIO1; MM(0,0,bq0); PRIO0; BAR; SB0;
    // P2: quad(0,1); stage buf1.B.h1 <- t+1
    RD_B(0, 1, bq1);
    STG(1,1,1, t+1);
    BAR; LGKM0; SB0; PRIO1; MM(0,1,bq1); PRIO0; BAR; SB0;
    // P3: quad(1,0); stage buf0.A.h0 <- t+2 (A0-h0 died at P2)
    RD_A(0, 1);
    if (more) STG(0,0,0, t+2);
    BAR; LGKM0; SB0; PRIO1; MM(1,0,bq0); PRIO0; BAR; SB0;
    // P4: quad(1,1); stage buf0.B.h0 <- t+2 (B0-h0 died at P3); vmcnt check
    if (more){ STG(0,1,0, t+2); VM4; } else { VM0; }
    BAR; SB0; PRIO1; MM(1,1,bq1); PRIO0; BAR; SB0;
    // P5: tile t+1 quad(0,0); stage buf0.A.h1 <- t+2 (died at P4)
    RD_A(1, 0); RD_B(1, 0, bq0);
    if (more) STG(0,0,1, t+2);
    BAR; LGKM0; SB0; PRIO1; MM(0,0,bq0); PRIO0; BAR; SB0;
    // P6: quad(0,1); stage buf0.B.h1 <- t+2 (died at P4)
    RD_B(1, 1, bq1);
    if (more) STG(0,1,1, t+2);
    BAR; LGKM0; SB0; PRIO1; MM(0,1,bq1); PRIO0; BAR; SB0;
    // P7: quad(1,0); stage buf1.A.h0 <- t+3 (A1-h0 died at P6)
    RD_A(1, 1);
    if (more) STG(1,0,0, t+3);
    BAR; LGKM0; SB0; PRIO1; MM(1,0,bq0); PRIO0; BAR; SB0;
    // P8: quad(1,1); stage buf1.B.h0 <- t+3 (died at P7); vmcnt check
    if (more){ STG(1,1,0, t+3); VM4; }
    BAR; SB0; PRIO1; MM(1,1,bq1); PRIO0; BAR; SB0;
  }

  // epilogue (D[row=q*4+reg][col=lane&15] per 16x16 fragment)
  #pragma unroll
  for (int qm = 0; qm < 2; qm++){
    #pragma unroll
    for (int i_ = 0; i_ < 4; i_++){
      #pragma unroll
      for (int r = 0; r < 4; r++){
        int grow = m0 + qm*128 + wmI*64 + i_*16 + q*4 + r;
        size_t orow = (size_t)grow;
        if (epi == EPI_PROJ){   // window-order row -> standard (b,h,w) row
          int win = grow / 196, loc = grow % 196;
          int b_ = win >> 4, wr = win & 15;
          int hh = (wr >> 2) * 14 + loc / 14;
          int ww = (wr & 3)  * 14 + loc % 14;
          orow = (size_t)((b_ * 56 + hh) * 56 + ww);
        }
        #pragma unroll
        for (int qn = 0; qn < 2; qn++){
          #pragma unroll
          for (int n_ = 0; n_ < 2; n_++){
            int col = n0 + qn*128 + wnI*32 + n_*16 + c;
            float v = acc[qm][qn][i_][n_][r] + bias[col];
            if (epi == EPI_PROJ){           // + x (shortcut), fp32 out
              v += residf[orow * 768 + col];
              ((float*)outp)[orow * (size_t)N + col] = v;
            } else if (epi == EPI_MLP2){    // + hidden, fp32 out (in-place safe)
              v += residf[(size_t)grow * 768 + col];
              ((float*)outp)[orow * (size_t)N + col] = v;
            } else {
              if (epi == EPI_GELU) v = 0.5f * v * (1.f + erff(v * 0.70710678f));
              ((u16*)outp)[orow * (size_t)N + col] = f2bf(v);
            }
          }
        }
      }
    }
  }
  #undef STG
  #undef RD_A
  #undef RD_B
  #undef MM
}

// ------------------------------------------------ attention (unchanged this round)
__global__ __launch_bounds__(256)
void attn_kernel(const u16* __restrict__ qkv, const u16* __restrict__ relh,
                 const u16* __restrict__ relw, u16* __restrict__ aout)
{
  __shared__ u16 Vt[64][232];          // [hd][token 0..223 +pad]; cols >=196 zeroed
  __shared__ u16 P[4][16*216 + 16];    // per-wave P tile, rows stride 216, 16-elem tail
  __shared__ u16 RB[4][16][56];        // per-wave bias: [row][dh 0..26 | 28+dw 0..26]
  const int blk = blockIdx.x;
  const int win = blk / 12, head = blk % 12;
  const int tid = threadIdx.x;
  const int wv = tid >> 6, lane = tid & 63;
  const int q = lane >> 4, c = lane & 15;
  const u16* base = qkv + (size_t)win * 196 * 2304 + head * 64;

  for (int i = tid; i < 64*36; i += 256) Vt[i / 36][196 + i % 36] = 0;
  for (int i = tid; i < 4*144; i += 256){
    int w = i / 144, r = i % 144;
    int off = (r < 128) ? ((r >> 3) * 216 + 208 + (r & 7)) : (16*216 + (r - 128));
    P[w][off] = 0;
  }
  for (int i = tid; i < 196*8; i += 256){
    int t = i >> 3, h8 = (i & 7) << 3;
    bf16x8 v = ld8(base + (size_t)t * 2304 + 1536 + h8);
    #pragma unroll
    for (int j = 0; j < 8; j++) Vt[h8 + j][t] = (u16)v[j];
  }
  __syncthreads();

  const float scale = 0.125f;   // 64^-0.5
  for (int mt = wv; mt < 13; mt += 4){
    const int m0 = mt * 16;
    int qr = m0 + c; if (qr > 195) qr = 195;
    const u16* qrow = base + (size_t)qr * 2304;
    bf16x8 aq0 = ld8(qrow + q*8);
    bf16x8 aq1 = ld8(qrow + 32 + q*8);

    f32x4 accs[13];
    #pragma unroll
    for (int nt = 0; nt < 13; nt++) accs[nt] = f4zero();
    #pragma unroll
    for (int nt = 0; nt < 13; nt++){
      int kt = nt*16 + c; if (kt > 195) kt = 195;
      const u16* krow = base + (size_t)kt * 2304 + 768;
      accs[nt] = MFMA16(aq0, ld8(krow + q*8), accs[nt]);
      accs[nt] = MFMA16(aq1, ld8(krow + 32 + q*8), accs[nt]);
    }

    f32x4 rha[2], rwa[2];
    #pragma unroll
    for (int ntt = 0; ntt < 2; ntt++){
      int dh = ntt*16 + c; if (dh > 26) dh = 26;
      const u16* ph = relh + dh*64;
      const u16* pw = relw + dh*64;
      rha[ntt] = MFMA16(aq0, ld8(ph + q*8), f4zero());
      rha[ntt] = MFMA16(aq1, ld8(ph + 32 + q*8), rha[ntt]);
      rwa[ntt] = MFMA16(aq0, ld8(pw + q*8), f4zero());
      rwa[ntt] = MFMA16(aq1, ld8(pw + 32 + q*8), rwa[ntt]);
    }
    #pragma unroll
    for (int ntt = 0; ntt < 2; ntt++)
      #pragma unroll
      for (int r = 0; r < 4; r++){
        int col = ntt*16 + c;
        if (col < 27){
          RB[wv][q*4+r][col]      = f2bf(rha[ntt][r]);
          RB[wv][q*4+r][28 + col] = f2bf(rwa[ntt][r]);
        }
      }

    #pragma unroll
    for (int r = 0; r < 4; r++){
      int it = m0 + q*4 + r; if (it > 195) it = 195;
      int hq = it / 14, wq = it % 14;
      float sv[13];
      float mx = -3e38f;
      #pragma unroll
      for (int nt = 0; nt < 13; nt++){
        int j = nt*16 + c;
        float x;
        if (j < 196){
          int hk = j / 14, wk = j % 14;
          x = accs[nt][r] * scale + bf2f(RB[wv][q*4+r][hq - hk + 13])
                                  + bf2f(RB[wv][q*4+r][28 + wq - wk + 13]);
        } else x = -3e38f;
        sv[nt] = x; mx = fmaxf(mx, x);
      }
      mx = fmaxf(mx, __shfl_xor(mx, 1, 64));
      mx = fmaxf(mx, __shfl_xor(mx, 2, 64));
      mx = fmaxf(mx, __shfl_xor(mx, 4, 64));
      mx = fmaxf(mx, __shfl_xor(mx, 8, 64));
      float sum = 0.f;
      #pragma unroll
      for (int nt = 0; nt < 13; nt++){ float p = __expf(sv[nt] - mx); sv[nt] = p; sum += p; }
      sum += __shfl_xor(sum, 1, 64); sum += __shfl_xor(sum, 2, 64);
      sum += __shfl_xor(sum, 4, 64); sum += __shfl_xor(sum, 8, 64);
      float is = 1.f / sum;
      #pragma unroll
      for (int nt = 0; nt < 13; nt++)
        P[wv][(q*4+r)*216 + nt*16 + c] = f2bf(sv[nt] * is);
    }

    f32x4 acco[4];
    #pragma unroll
    for (int nv = 0; nv < 4; nv++) acco[nv] = f4zero();
    #pragma unroll
    for (int ks = 0; ks < 7; ks++){
      bf16x8 ap = ld8(&P[wv][c*216 + ks*32 + q*8]);
      #pragma unroll
      for (int nv = 0; nv < 4; nv++){
        bf16x8 bv = ld8(&Vt[nv*16 + c][ks*32 + q*8]);
        acco[nv] = MFMA16(ap, bv, acco[nv]);
      }
    }
    #pragma unroll
    for (int nv = 0; nv < 4; nv++)
      #pragma unroll
      for (int r = 0; r < 4; r++){
        int it = m0 + q*4 + r;
        if (it < 196)
          aout[(size_t)(win*196 + it)*768 + head*64 + nv*16 + c] = f2bf(acco[nv][r]);
      }
  }
}

// ------------------------------------------------ launch
extern "C" void kernel_launch(void* const* d_in, const int* in_sizes, int n_in,
                              void* d_out, int out_size, void* d_ws, size_t ws_size,
                              hipStream_t stream)
{
  (void)in_sizes; (void)n_in; (void)out_size; (void)ws_size;
  const float* x      = (const float*)d_in[0];
  const float* n1g    = (const float*)d_in[1];
  const float* n1b    = (const float*)d_in[2];
  const float* qkv_w  = (const float*)d_in[3];
  const float* qkv_b  = (const float*)d_in[4];
  const float* proj_w = (const float*)d_in[5];
  const float* proj_b = (const float*)d_in[6];
  const float* relh   = (const float*)d_in[7];
  const float* relw   = (const float*)d_in[8];
  const float* n2g    = (const float*)d_in[9];
  const float* n2b    = (const float*)d_in[10];
  const float* lin1_w = (const float*)d_in[11];
  const float* lin1_b = (const float*)d_in[12];
  const float* lin2_w = (const float*)d_in[13];
  const float* lin2_b = (const float*)d_in[14];
  float* out = (float*)d_out;   // also serves as fp32 'hidden' buffer

  char* ws = (char*)d_ws;
  u16* qkvwt  = (u16*)(ws);                        //  3,538,944 B
  u16* projwt = (u16*)(ws +  3538944);             //  1,179,648 B
  u16* lin1wt = (u16*)(ws +  4718592);             //  4,718,592 B
  u16* lin2wt = (u16*)(ws +  9437184);             //  4,718,592 B
  u16* relhb  = (u16*)(ws + 14155776);             //      3,456 B
  u16* relwb  = (u16*)(ws + 14159232);             //      3,456 B
  u16* bufA   = (u16*)(ws + 14162688);             // 77,070,336 B: ln1out -> attnout -> normed
  u16* bufQ   = (u16*)(ws + 14162688 + (size_t)77070336); // 231,211,008 B: qkv -> m1 chunks

  conv_transpose<<<(768/32)*(2304/32), 256, 0, stream>>>(qkv_w,  qkvwt, 768, 2304);
  conv_transpose<<<(768/32)*(768/32),  256, 0, stream>>>(proj_w, projwt, 768, 768);
  conv_transpose<<<(768/32)*(3072/32), 256, 0, stream>>>(lin1_w, lin1wt, 768, 3072);
  conv_transpose<<<(3072/32)*(768/32), 256, 0, stream>>>(lin2_w, lin2wt, 3072, 768);
  conv_bf16<<<(27*64 + 255)/256, 256, 0, stream>>>(relh, relw, relhb, relwb, 27*64);

  // LN1 (window-ordered bf16) -> QKV GEMM -> attention
  ln_kernel<<<12544, 256, 0, stream>>>(x, n1g, n1b, bufA, 1);
  gemm256<<<196*9, 512, 0, stream>>>(bufA, qkvwt, qkv_b, nullptr, bufQ,
                                     50176, 2304, 768, EPI_QKV);
  attn_kernel<<<3072, 256, 0, stream>>>(bufQ, relhb, relwb, bufA);
  // proj + residual -> hidden (fp32, in d_out)
  gemm256<<<196*3, 512, 0, stream>>>(bufA, projwt, proj_b, x, out,
                                     50176, 768, 768, EPI_PROJ);
  // LN2 -> MLP (2 halves; m1 reuses bufQ)
  ln_kernel<<<12544, 256, 0, stream>>>(out, n2g, n2b, bufA, 0);
  for (int h = 0; h < 2; h++){
    const u16* nrm = bufA + (size_t)h * 25088 * 768;
    float* hid     = out  + (size_t)h * 25088 * 768;
    gemm256<<<98*12, 512, 0, stream>>>(nrm, lin1wt, lin1_b, nullptr, bufQ,
                                       25088, 3072, 768, EPI_GELU);
    gemm256<<<98*3, 512, 0, stream>>>(bufQ, lin2wt, lin2_b, hid, hid,
                                      25088, 768, 3072, EPI_MLP2);
  }
}

// Round 4
// 1832.997 us; speedup vs baseline: 1.3612x; 1.2842x over previous
//
#include <hip/hip_runtime.h>
#include <cstdint>
#include <cstddef>

// ViT block (SAM-style windowed attention, 14x14 windows, decomposed rel-pos).
// I/O fp32 (per reference); internal GEMM/attention compute in bf16 MFMA, fp32 acc.
// R4: GEMM back to the verified m97 structure (R1), with two occupancy/locality
//     fixes: template<int EPI> so each launch compiles a lean epilogue (runtime
//     4-way branch was inflating the VGPR union), __launch_bounds__(256,3) to pin
//     3 waves/EU (3 blocks/CU, m114 cross-block overlap), and bijective XCD-chunk
//     blockIdx swizzle (all grids %8==0) for A-panel L2 reuse. Attention unchanged.

typedef unsigned short u16;
typedef __attribute__((ext_vector_type(8))) short bf16x8;   // 8 bf16 = 4 VGPRs
typedef __attribute__((ext_vector_type(4))) short bf16x4;   // 8B
typedef __attribute__((ext_vector_type(4))) float f32x4;

#define MFMA16(a,b,c) __builtin_amdgcn_mfma_f32_16x16x32_bf16(a,b,c,0,0,0)

__device__ __forceinline__ float bf2f(u16 u){
  union { unsigned int i; float f; } v; v.i = ((unsigned int)u) << 16; return v.f;
}
__device__ __forceinline__ u16 f2bf(float f){
  union { float f; unsigned int i; } v; v.f = f;
  unsigned int r = v.i + 0x7FFFu + ((v.i >> 16) & 1u);   // RNE
  return (u16)(r >> 16);
}
__device__ __forceinline__ f32x4 f4zero(){ f32x4 z; z[0]=z[1]=z[2]=z[3]=0.f; return z; }
__device__ __forceinline__ bf16x8 ld8(const u16* p){ return *reinterpret_cast<const bf16x8*>(p); }

// async global->LDS, 16B per lane. LDS dest = wave-uniform base + lane*16.
__device__ __forceinline__ void gld_lds16(const u16* g, u16* l){
  __builtin_amdgcn_global_load_lds(
      (const __attribute__((address_space(1))) unsigned int*)(g),
      (__attribute__((address_space(3))) unsigned int*)(l), 16, 0, 0);
}

// ------------------------------------------------ weight convert+transpose (fp32 -> bf16^T)
__global__ __launch_bounds__(256)
void conv_transpose(const float* __restrict__ in, u16* __restrict__ out, int R, int C)
{
  __shared__ float tile[32][33];
  int cb = C >> 5;
  int bx = blockIdx.x % cb, by = blockIdx.x / cb;
  int c0 = bx << 5, r0 = by << 5;
  int tx = threadIdx.x & 31, ty = threadIdx.x >> 5;   // ty 0..7
  #pragma unroll
  for (int k = 0; k < 4; k++)
    tile[ty + 8*k][tx] = in[(size_t)(r0 + ty + 8*k) * C + c0 + tx];
  __syncthreads();
  #pragma unroll
  for (int k = 0; k < 4; k++)
    out[(size_t)(c0 + ty + 8*k) * R + r0 + tx] = f2bf(tile[tx][ty + 8*k]);
}

// ------------------------------------------------ rel-pos table convert (fp32 -> bf16)
__global__ __launch_bounds__(256)
void conv_bf16(const float* __restrict__ a, const float* __restrict__ b,
               u16* __restrict__ oa, u16* __restrict__ ob, int n)
{
  int i = blockIdx.x * 256 + threadIdx.x;
  if (i < n){ oa[i] = f2bf(a[i]); ob[i] = f2bf(b[i]); }
}

// ------------------------------------------------ layernorm (fp32 in -> bf16 out)
// one wave per token (4 tokens/block). window_map=1: write rows window-partitioned.
__global__ __launch_bounds__(256)
void ln_kernel(const float* __restrict__ in, const float* __restrict__ g,
               const float* __restrict__ b, u16* __restrict__ out, int window_map)
{
  const int wv = threadIdx.x >> 6, lane = threadIdx.x & 63;
  const int token = blockIdx.x * 4 + wv;
  const float* row = in + (size_t)token * 768;
  float vals[12];
  float s = 0.f, s2 = 0.f;
  #pragma unroll
  for (int j = 0; j < 3; j++){
    float4 u = *reinterpret_cast<const float4*>(row + j*256 + lane*4);
    float t[4] = {u.x, u.y, u.z, u.w};
    #pragma unroll
    for (int e = 0; e < 4; e++){ vals[j*4+e] = t[e]; s += t[e]; s2 += t[e]*t[e]; }
  }
  #pragma unroll
  for (int m = 1; m < 64; m <<= 1){ s += __shfl_xor(s, m, 64); s2 += __shfl_xor(s2, m, 64); }
  float mu  = s  * (1.f/768.f);
  float var = s2 * (1.f/768.f) - mu*mu;
  float rs  = rsqrtf(var + 1e-5f);
  size_t orow = (size_t)token;
  if (window_map){
    int b_ = token / 3136, rem = token % 3136;
    int hh = rem / 56, ww = rem % 56;
    int win = ((b_ << 2) + hh/14)*4 + ww/14;
    orow = (size_t)win * 196 + (hh%14)*14 + (ww%14);
  }
  u16* op = out + orow * 768;
  #pragma unroll
  for (int j = 0; j < 3; j++){
    int cb = j*256 + lane*4;
    float4 gg = *reinterpret_cast<const float4*>(g + cb);
    float4 bb = *reinterpret_cast<const float4*>(b + cb);
    float gt[4] = {gg.x, gg.y, gg.z, gg.w};
    float bt[4] = {bb.x, bb.y, bb.z, bb.w};
    bf16x4 o;
    #pragma unroll
    for (int e = 0; e < 4; e++)
      o[e] = (short)f2bf((vals[j*4+e] - mu) * rs * gt[e] + bt[e]);
    *reinterpret_cast<bf16x4*>(op + cb) = o;
  }
}

// ------------------------------------------------ GEMM (m97-style, R1-verified)
// C[M,N] = A[M,K] @ Bt[N,K]^T (+bias +epilogue). 128x128 tile, 4 waves of 64x64.
// Staging: global_load_lds dwordx4 into LINEAR LDS tiles [128][32].
// Verified fragment layouts: A[m=lane&15][k=quad*8+j], B[k=quad*8+j][n=lane&15],
// D[row=quad*4+reg][col=lane&15].
// R4: template<EPI> (lean per-launch epilogue), __launch_bounds__(256,3) for
// 3 blocks/CU, XCD-chunk swizzle (grids %8==0 -> bijective).
enum { EPI_QKV = 0, EPI_PROJ = 1, EPI_GELU = 2, EPI_MLP2 = 3 };

template<int EPI>
__global__ __launch_bounds__(256, 3)
void gemm_bt(const u16* __restrict__ A, const u16* __restrict__ Bt,
             const float* __restrict__ bias, const float* __restrict__ residf,
             void* __restrict__ outp, int N, int K)
{
  __shared__ __align__(16) u16 As[128][32];
  __shared__ __align__(16) u16 Bs[128][32];
  const int nb = N >> 7;
  // XCD-chunk swizzle: contiguous wg range per XCD -> A-panel L2 reuse.
  const int nwg = gridDim.x;
  const int bid = blockIdx.x;
  const int wg = (nwg & 7) ? bid : ((bid & 7) * (nwg >> 3) + (bid >> 3));
  const int bm = wg / nb, bn = wg % nb;
  const int m0 = bm << 7, n0 = bn << 7;
  const int tid = threadIdx.x;
  const int wv = tid >> 6, lane = tid & 63;
  const int wm = (wv & 1) << 6, wn = (wv >> 1) << 6;
  const int q = lane >> 4, c = lane & 15;

  f32x4 acc[4][4];
  #pragma unroll
  for (int i = 0; i < 4; i++)
    #pragma unroll
    for (int j = 0; j < 4; j++) acc[i][j] = f4zero();

  // staging: wave wv owns rows [wv*32, wv*32+32) of each tile, 2 instrs of 16 rows.
  // instr writes LDS base + lane*16B -> row base+lane/4, cols (lane&3)*8..+8 (u16).
  const int r0 = (wv << 5) + (lane >> 2);
  const int cq = (lane & 3) << 3;
  const u16* pa = A  + (size_t)(m0 + r0) * K + cq;
  const u16* pb = Bt + (size_t)(n0 + r0) * K + cq;
  const size_t skip = (size_t)16 * K;          // 16 rows ahead
  u16* lA0 = &As[wv << 5][0];
  u16* lA1 = &As[(wv << 5) + 16][0];
  u16* lB0 = &Bs[wv << 5][0];
  u16* lB1 = &Bs[(wv << 5) + 16][0];

  for (int k0 = 0; k0 < K; k0 += 32){
    gld_lds16(pa + k0,        lA0);
    gld_lds16(pa + skip + k0, lA1);
    gld_lds16(pb + k0,        lB0);
    gld_lds16(pb + skip + k0, lB1);
    __syncthreads();                 // compiler drains vmcnt before barrier
    bf16x8 af[4], bfr[4];
    #pragma unroll
    for (int mi = 0; mi < 4; mi++) af[mi]  = ld8(&As[wm + mi*16 + c][q*8]);
    #pragma unroll
    for (int ni = 0; ni < 4; ni++) bfr[ni] = ld8(&Bs[wn + ni*16 + c][q*8]);
    #pragma unroll
    for (int mi = 0; mi < 4; mi++)
      #pragma unroll
      for (int ni = 0; ni < 4; ni++)
        acc[mi][ni] = MFMA16(af[mi], bfr[ni], acc[mi][ni]);
    __syncthreads();                 // LDS safe to overwrite next iter
  }

  // epilogue
  #pragma unroll
  for (int mi = 0; mi < 4; mi++){
    #pragma unroll
    for (int r = 0; r < 4; r++){
      int grow = m0 + wm + mi*16 + q*4 + r;
      size_t orow = (size_t)grow;
      if constexpr (EPI == EPI_PROJ){   // window-order row -> standard (b,h,w) row
        int win = grow / 196, loc = grow % 196;
        int b_ = win >> 4, wr = win & 15;
        int hh = (wr >> 2) * 14 + loc / 14;
        int ww = (wr & 3)  * 14 + loc % 14;
        orow = (size_t)((b_ * 56 + hh) * 56 + ww);
      }
      #pragma unroll
      for (int ni = 0; ni < 4; ni++){
        int col = n0 + wn + ni*16 + c;
        float v = acc[mi][ni][r] + bias[col];
        if constexpr (EPI == EPI_PROJ){           // + x (shortcut), fp32 out
          v += residf[orow * 768 + col];
          ((float*)outp)[orow * (size_t)N + col] = v;
        } else if constexpr (EPI == EPI_MLP2){    // + hidden, fp32 out (in-place safe)
          v += residf[(size_t)grow * 768 + col];
          ((float*)outp)[orow * (size_t)N + col] = v;
        } else {
          if constexpr (EPI == EPI_GELU) v = 0.5f * v * (1.f + erff(v * 0.70710678f));
          ((u16*)outp)[orow * (size_t)N + col] = f2bf(v);
        }
      }
    }
  }
}

// ------------------------------------------------ attention (unchanged this round)
// one block per (window, head). 4 waves; wave handles m-tiles {wv, wv+4, ...} of 13.
__global__ __launch_bounds__(256)
void attn_kernel(const u16* __restrict__ qkv, const u16* __restrict__ relh,
                 const u16* __restrict__ relw, u16* __restrict__ aout)
{
  __shared__ u16 Vt[64][232];          // [hd][token 0..223 +pad]; cols >=196 zeroed
  __shared__ u16 P[4][16*216 + 16];    // per-wave P tile, rows stride 216, 16-elem tail
  __shared__ u16 RB[4][16][56];        // per-wave bias: [row][dh 0..26 | 28+dw 0..26]
  const int blk = blockIdx.x;
  const int win = blk / 12, head = blk % 12;
  const int tid = threadIdx.x;
  const int wv = tid >> 6, lane = tid & 63;
  const int q = lane >> 4, c = lane & 15;
  const u16* base = qkv + (size_t)win * 196 * 2304 + head * 64;

  for (int i = tid; i < 64*36; i += 256) Vt[i / 36][196 + i % 36] = 0;
  for (int i = tid; i < 4*144; i += 256){
    int w = i / 144, r = i % 144;
    int off = (r < 128) ? ((r >> 3) * 216 + 208 + (r & 7)) : (16*216 + (r - 128));
    P[w][off] = 0;
  }
  for (int i = tid; i < 196*8; i += 256){
    int t = i >> 3, h8 = (i & 7) << 3;
    bf16x8 v = ld8(base + (size_t)t * 2304 + 1536 + h8);
    #pragma unroll
    for (int j = 0; j < 8; j++) Vt[h8 + j][t] = (u16)v[j];
  }
  __syncthreads();

  const float scale = 0.125f;   // 64^-0.5
  for (int mt = wv; mt < 13; mt += 4){
    const int m0 = mt * 16;
    int qr = m0 + c; if (qr > 195) qr = 195;
    const u16* qrow = base + (size_t)qr * 2304;
    bf16x8 aq0 = ld8(qrow + q*8);
    bf16x8 aq1 = ld8(qrow + 32 + q*8);

    f32x4 accs[13];
    #pragma unroll
    for (int nt = 0; nt < 13; nt++) accs[nt] = f4zero();
    #pragma unroll
    for (int nt = 0; nt < 13; nt++){
      int kt = nt*16 + c; if (kt > 195) kt = 195;
      const u16* krow = base + (size_t)kt * 2304 + 768;
      accs[nt] = MFMA16(aq0, ld8(krow + q*8), accs[nt]);
      accs[nt] = MFMA16(aq1, ld8(krow + 32 + q*8), accs[nt]);
    }

    f32x4 rha[2], rwa[2];
    #pragma unroll
    for (int ntt = 0; ntt < 2; ntt++){
      int dh = ntt*16 + c; if (dh > 26) dh = 26;
      const u16* ph = relh + dh*64;
      const u16* pw = relw + dh*64;
      rha[ntt] = MFMA16(aq0, ld8(ph + q*8), f4zero());
      rha[ntt] = MFMA16(aq1, ld8(ph + 32 + q*8), rha[ntt]);
      rwa[ntt] = MFMA16(aq0, ld8(pw + q*8), f4zero());
      rwa[ntt] = MFMA16(aq1, ld8(pw + 32 + q*8), rwa[ntt]);
    }
    #pragma unroll
    for (int ntt = 0; ntt < 2; ntt++)
      #pragma unroll
      for (int r = 0; r < 4; r++){
        int col = ntt*16 + c;
        if (col < 27){
          RB[wv][q*4+r][col]      = f2bf(rha[ntt][r]);
          RB[wv][q*4+r][28 + col] = f2bf(rwa[ntt][r]);
        }
      }

    #pragma unroll
    for (int r = 0; r < 4; r++){
      int it = m0 + q*4 + r; if (it > 195) it = 195;
      int hq = it / 14, wq = it % 14;
      float sv[13];
      float mx = -3e38f;
      #pragma unroll
      for (int nt = 0; nt < 13; nt++){
        int j = nt*16 + c;
        float x;
        if (j < 196){
          int hk = j / 14, wk = j % 14;
          x = accs[nt][r] * scale + bf2f(RB[wv][q*4+r][hq - hk + 13])
                                  + bf2f(RB[wv][q*4+r][28 + wq - wk + 13]);
        } else x = -3e38f;
        sv[nt] = x; mx = fmaxf(mx, x);
      }
      mx = fmaxf(mx, __shfl_xor(mx, 1, 64));
      mx = fmaxf(mx, __shfl_xor(mx, 2, 64));
      mx = fmaxf(mx, __shfl_xor(mx, 4, 64));
      mx = fmaxf(mx, __shfl_xor(mx, 8, 64));
      float sum = 0.f;
      #pragma unroll
      for (int nt = 0; nt < 13; nt++){ float p = __expf(sv[nt] - mx); sv[nt] = p; sum += p; }
      sum += __shfl_xor(sum, 1, 64); sum += __shfl_xor(sum, 2, 64);
      sum += __shfl_xor(sum, 4, 64); sum += __shfl_xor(sum, 8, 64);
      float is = 1.f / sum;
      #pragma unroll
      for (int nt = 0; nt < 13; nt++)
        P[wv][(q*4+r)*216 + nt*16 + c] = f2bf(sv[nt] * is);
    }

    f32x4 acco[4];
    #pragma unroll
    for (int nv = 0; nv < 4; nv++) acco[nv] = f4zero();
    #pragma unroll
    for (int ks = 0; ks < 7; ks++){
      bf16x8 ap = ld8(&P[wv][c*216 + ks*32 + q*8]);
      #pragma unroll
      for (int nv = 0; nv < 4; nv++){
        bf16x8 bv = ld8(&Vt[nv*16 + c][ks*32 + q*8]);
        acco[nv] = MFMA16(ap, bv, acco[nv]);
      }
    }
    #pragma unroll
    for (int nv = 0; nv < 4; nv++)
      #pragma unroll
      for (int r = 0; r < 4; r++){
        int it = m0 + q*4 + r;
        if (it < 196)
          aout[(size_t)(win*196 + it)*768 + head*64 + nv*16 + c] = f2bf(acco[nv][r]);
      }
  }
}

// ------------------------------------------------ launch
extern "C" void kernel_launch(void* const* d_in, const int* in_sizes, int n_in,
                              void* d_out, int out_size, void* d_ws, size_t ws_size,
                              hipStream_t stream)
{
  (void)in_sizes; (void)n_in; (void)out_size; (void)ws_size;
  const float* x      = (const float*)d_in[0];
  const float* n1g    = (const float*)d_in[1];
  const float* n1b    = (const float*)d_in[2];
  const float* qkv_w  = (const float*)d_in[3];
  const float* qkv_b  = (const float*)d_in[4];
  const float* proj_w = (const float*)d_in[5];
  const float* proj_b = (const float*)d_in[6];
  const float* relh   = (const float*)d_in[7];
  const float* relw   = (const float*)d_in[8];
  const float* n2g    = (const float*)d_in[9];
  const float* n2b    = (const float*)d_in[10];
  const float* lin1_w = (const float*)d_in[11];
  const float* lin1_b = (const float*)d_in[12];
  const float* lin2_w = (const float*)d_in[13];
  const float* lin2_b = (const float*)d_in[14];
  float* out = (float*)d_out;   // also serves as fp32 'hidden' buffer

  char* ws = (char*)d_ws;
  u16* qkvwt  = (u16*)(ws);                        //  3,538,944 B
  u16* projwt = (u16*)(ws +  3538944);             //  1,179,648 B
  u16* lin1wt = (u16*)(ws +  4718592);             //  4,718,592 B
  u16* lin2wt = (u16*)(ws +  9437184);             //  4,718,592 B
  u16* relhb  = (u16*)(ws + 14155776);             //      3,456 B
  u16* relwb  = (u16*)(ws + 14159232);             //      3,456 B
  u16* bufA   = (u16*)(ws + 14162688);             // 77,070,336 B: ln1out -> attnout -> normed
  u16* bufQ   = (u16*)(ws + 14162688 + (size_t)77070336); // 231,211,008 B: qkv -> m1 chunks
  // total ws usage: 322,444,032 B

  conv_transpose<<<(768/32)*(2304/32), 256, 0, stream>>>(qkv_w,  qkvwt, 768, 2304);
  conv_transpose<<<(768/32)*(768/32),  256, 0, stream>>>(proj_w, projwt, 768, 768);
  conv_transpose<<<(768/32)*(3072/32), 256, 0, stream>>>(lin1_w, lin1wt, 768, 3072);
  conv_transpose<<<(3072/32)*(768/32), 256, 0, stream>>>(lin2_w, lin2wt, 3072, 768);
  conv_bf16<<<(27*64 + 255)/256, 256, 0, stream>>>(relh, relw, relhb, relwb, 27*64);

  // LN1 (window-ordered bf16) -> QKV GEMM -> attention
  ln_kernel<<<12544, 256, 0, stream>>>(x, n1g, n1b, bufA, 1);
  gemm_bt<EPI_QKV><<<392*18, 256, 0, stream>>>(bufA, qkvwt, qkv_b, nullptr, bufQ,
                                               2304, 768);
  attn_kernel<<<3072, 256, 0, stream>>>(bufQ, relhb, relwb, bufA);
  // proj + residual -> hidden (fp32, in d_out)
  gemm_bt<EPI_PROJ><<<392*6, 256, 0, stream>>>(bufA, projwt, proj_b, x, out,
                                               768, 768);
  // LN2 -> MLP (2 halves; m1 reuses bufQ)
  ln_kernel<<<12544, 256, 0, stream>>>(out, n2g, n2b, bufA, 0);
  for (int h = 0; h < 2; h++){
    const u16* nrm = bufA + (size_t)h * 25088 * 768;
    float* hid     = out  + (size_t)h * 25088 * 768;
    gemm_bt<EPI_GELU><<<196*24, 256, 0, stream>>>(nrm, lin1wt, lin1_b, nullptr, bufQ,
                                                  3072, 768);
    gemm_bt<EPI_MLP2><<<196*6, 256, 0, stream>>>(bufQ, lin2wt, lin2_b, hid, hid,
                                                 768, 3072);
  }
}